// Round 12
// baseline (59.323 us; speedup 1.0000x reference)
//
#include <hip/hip_runtime.h>
#include <hip/hip_bf16.h>

#define N_ 4096
#define D_ 768
#define NCLS 128
#define BM 128
#define BN 128
#define BK 64
#define NSTEP 12  // D_/BK

typedef __bf16 bf16x8 __attribute__((ext_vector_type(8)));
typedef float f32x4 __attribute__((ext_vector_type(4)));
typedef short s16x8 __attribute__((ext_vector_type(8)));

// Normalize: one wave per row, no block sync. blocks*4 rows; [0,N)->img, [N,2N)->txt.
__global__ __launch_bounds__(256) void normalize_kernel(
    const float* __restrict__ img, const float* __restrict__ txt,
    __hip_bfloat16* __restrict__ img_nb, __hip_bfloat16* __restrict__ txt_nb) {
  int idx = blockIdx.x * 4 + (threadIdx.x >> 6);  // row 0..8191
  int lane = threadIdx.x & 63;
  const float* s;
  __hip_bfloat16* d;
  if (idx < N_) {
    s = img + (size_t)idx * D_;
    d = img_nb + (size_t)idx * D_;
  } else {
    s = txt + (size_t)(idx - N_) * D_;
    d = txt_nb + (size_t)(idx - N_) * D_;
  }
  float4 v0 = ((const float4*)s)[lane];
  float4 v1 = ((const float4*)s)[lane + 64];
  float4 v2 = ((const float4*)s)[lane + 128];
  float ss = v0.x * v0.x + v0.y * v0.y + v0.z * v0.z + v0.w * v0.w +
             v1.x * v1.x + v1.y * v1.y + v1.z * v1.z + v1.w * v1.w +
             v2.x * v2.x + v2.y * v2.y + v2.z * v2.z + v2.w * v2.w;
#pragma unroll
  for (int m = 32; m; m >>= 1) ss += __shfl_xor(ss, m);
  float inv = 1.0f / fmaxf(sqrtf(ss), 1e-8f);
  ushort4 o0, o1, o2;
  o0.x = __bfloat16_as_ushort(__float2bfloat16(v0.x * inv));
  o0.y = __bfloat16_as_ushort(__float2bfloat16(v0.y * inv));
  o0.z = __bfloat16_as_ushort(__float2bfloat16(v0.z * inv));
  o0.w = __bfloat16_as_ushort(__float2bfloat16(v0.w * inv));
  o1.x = __bfloat16_as_ushort(__float2bfloat16(v1.x * inv));
  o1.y = __bfloat16_as_ushort(__float2bfloat16(v1.y * inv));
  o1.z = __bfloat16_as_ushort(__float2bfloat16(v1.z * inv));
  o1.w = __bfloat16_as_ushort(__float2bfloat16(v1.w * inv));
  o2.x = __bfloat16_as_ushort(__float2bfloat16(v2.x * inv));
  o2.y = __bfloat16_as_ushort(__float2bfloat16(v2.y * inv));
  o2.z = __bfloat16_as_ushort(__float2bfloat16(v2.z * inv));
  o2.w = __bfloat16_as_ushort(__float2bfloat16(v2.w * inv));
  ((ushort4*)d)[lane] = o0;
  ((ushort4*)d)[lane + 64] = o1;
  ((ushort4*)d)[lane + 128] = o2;
}

// 128x128-tile bf16 GEMM, double-buffered, ONE barrier per K-step.
// Step order: read ks0 frags -> ds_write(u+1) -> MFMA ks0 -> read ks1 -> MFMA ks1
// -> global prefetch (u+2) -> barrier. Reads issued BEFORE writes so the first
// MFMA's lgkmcnt wait excludes the write drain (LDS ops complete in order).
// Same measured-0-conflict swizzle: pos(row,g) = row*8 + (g^(row&7)).
__global__ __launch_bounds__(256) void gemm_epi_kernel(
    const unsigned short* __restrict__ A, const unsigned short* __restrict__ B,
    const int* __restrict__ labels, float* __restrict__ row_part,
    float* __restrict__ col_part, float* __restrict__ S_part) {
  __shared__ __align__(16) unsigned short As[2][8192];
  __shared__ __align__(16) unsigned short Bs[2][8192];
  __shared__ int labR[BM], labC[BN];
  __shared__ float rbuf[2][BM], cbuf[2][BN];
  __shared__ float sbuf[4];

  const int bx = blockIdx.x, by = blockIdx.y;
  const int tid = threadIdx.x;
  const int lane = tid & 63, wave = tid >> 6;
  const int wr = wave >> 1, wc = wave & 1;
  const int g = lane >> 4, fr = lane & 15;
  const int rowBase = by * BM, colBase = bx * BN;

  if (tid < BM) labR[tid] = labels[rowBase + tid];
  else labC[tid - BM] = labels[colBase + tid - BM];

  const int gq = tid & 7, rbase = tid >> 3;
  const unsigned short* pa = A + (size_t)(rowBase + rbase) * D_ + gq * 8;
  const unsigned short* pb = B + (size_t)(colBase + rbase) * D_ + gq * 8;
  const int wpos = (rbase * 8 + (gq ^ (rbase & 7))) * 8;  // + j*2048

  f32x4 acc[4][4] = {};

  // prologue: write step 0 into buf0; load step 1 into regs
  s16x8 ra[4], rb[4];
#pragma unroll
  for (int j = 0; j < 4; ++j) {
    ra[j] = *(const s16x8*)(pa + (size_t)(32 * j) * D_);
    rb[j] = *(const s16x8*)(pb + (size_t)(32 * j) * D_);
  }
#pragma unroll
  for (int j = 0; j < 4; ++j) {
    *(s16x8*)&As[0][wpos + j * 2048] = ra[j];
    *(s16x8*)&Bs[0][wpos + j * 2048] = rb[j];
  }
#pragma unroll
  for (int j = 0; j < 4; ++j) {
    ra[j] = *(const s16x8*)(pa + (size_t)(32 * j) * D_ + BK);
    rb[j] = *(const s16x8*)(pb + (size_t)(32 * j) * D_ + BK);
  }
  __syncthreads();  // buf0 resident

  for (int u = 0; u < NSTEP; ++u) {
    const unsigned short* as_ = As[u & 1];
    const unsigned short* bs_ = Bs[u & 1];
    bf16x8 af[4], bf[4];
    {  // ks=0 fragment reads FIRST
      const int sw = g ^ (fr & 7);
#pragma unroll
      for (int m = 0; m < 4; ++m)
        af[m] = *(const bf16x8*)&as_[((wr * 64 + m * 16 + fr) * 8 + sw) * 8];
#pragma unroll
      for (int n = 0; n < 4; ++n)
        bf[n] = *(const bf16x8*)&bs_[((wc * 64 + n * 16 + fr) * 8 + sw) * 8];
    }
    if (u + 1 < NSTEP) {  // write u+1 into other buffer (drains under MFMA ks0)
      unsigned short* aw = As[(u + 1) & 1];
      unsigned short* bw = Bs[(u + 1) & 1];
#pragma unroll
      for (int j = 0; j < 4; ++j) {
        *(s16x8*)&aw[wpos + j * 2048] = ra[j];
        *(s16x8*)&bw[wpos + j * 2048] = rb[j];
      }
    }
#pragma unroll
    for (int m = 0; m < 4; ++m)
#pragma unroll
      for (int n = 0; n < 4; ++n)
        acc[m][n] = __builtin_amdgcn_mfma_f32_16x16x32_bf16(af[m], bf[n], acc[m][n], 0, 0, 0);
    {  // ks=1
      const int sw = (4 + g) ^ (fr & 7);
#pragma unroll
      for (int m = 0; m < 4; ++m)
        af[m] = *(const bf16x8*)&as_[((wr * 64 + m * 16 + fr) * 8 + sw) * 8];
#pragma unroll
      for (int n = 0; n < 4; ++n)
        bf[n] = *(const bf16x8*)&bs_[((wc * 64 + n * 16 + fr) * 8 + sw) * 8];
    }
#pragma unroll
    for (int m = 0; m < 4; ++m)
#pragma unroll
      for (int n = 0; n < 4; ++n)
        acc[m][n] = __builtin_amdgcn_mfma_f32_16x16x32_bf16(af[m], bf[n], acc[m][n], 0, 0, 0);
    if (u + 2 < NSTEP) {  // global prefetch (regs freed by the writes above)
      const int k0 = (u + 2) * BK;
#pragma unroll
      for (int j = 0; j < 4; ++j) {
        ra[j] = *(const s16x8*)(pa + (size_t)(32 * j) * D_ + k0);
        rb[j] = *(const s16x8*)(pb + (size_t)(32 * j) * D_ + k0);
      }
    }
    __syncthreads();
  }

  const float scale = 14.285714285714286f;  // 1/0.07
  float sPart = 0.f;
  float colAcc[4] = {0.f, 0.f, 0.f, 0.f};
#pragma unroll
  for (int m = 0; m < 4; ++m) {
    float ra2[4] = {0.f, 0.f, 0.f, 0.f};
#pragma unroll
    for (int n = 0; n < 4; ++n) {
      int col = wc * 64 + n * 16 + fr;
      int lc = labC[col];
#pragma unroll
      for (int r = 0; r < 4; ++r) {
        float v = acc[m][n][r] * scale;
        float e = __expf(v);
        ra2[r] += e;
        colAcc[n] += e;
        int row = wr * 64 + m * 16 + g * 4 + r;
        if (labR[row] == lc) sPart += v;
      }
    }
#pragma unroll
    for (int r = 0; r < 4; ++r) {
      float x = ra2[r];
      x += __shfl_xor(x, 1);
      x += __shfl_xor(x, 2);
      x += __shfl_xor(x, 4);
      x += __shfl_xor(x, 8);
      if (fr == 0) rbuf[wc][wr * 64 + m * 16 + g * 4 + r] = x;
    }
  }
#pragma unroll
  for (int n = 0; n < 4; ++n) {
    float x = colAcc[n];
    x += __shfl_xor(x, 16);
    x += __shfl_xor(x, 32);
    if (g == 0) cbuf[wr][wc * 64 + n * 16 + fr] = x;
  }
  float s = sPart;
#pragma unroll
  for (int m = 32; m; m >>= 1) s += __shfl_xor(s, m);
  if (lane == 0) sbuf[wave] = s;
  __syncthreads();
  if (tid < BM)
    row_part[(size_t)bx * N_ + rowBase + tid] = rbuf[0][tid] + rbuf[1][tid];
  else
    col_part[(size_t)by * N_ + colBase + (tid - BM)] = cbuf[0][tid - BM] + cbuf[1][tid - BM];
  if (tid == 0) S_part[by * 32 + bx] = sbuf[0] + sbuf[1] + sbuf[2] + sbuf[3];
}

// Final reduction: per-block hist + partial sums, double atomics + last-block-done
// writes the scalar loss (final_kernel launch eliminated).
__global__ __launch_bounds__(256) void reduce_kernel(
    const float* __restrict__ row_part, const float* __restrict__ col_part,
    const float* __restrict__ S_part, const int* __restrict__ labels,
    double* __restrict__ accs, unsigned* __restrict__ cnt, float* __restrict__ out) {
  __shared__ int hist[NCLS];
  int tid = threadIdx.x;
  if (tid < NCLS) hist[tid] = 0;
  __syncthreads();
  for (int j = tid; j < N_; j += 256) atomicAdd(&hist[labels[j]], 1);
  __syncthreads();

  int i = blockIdx.x * 256 + tid;  // 0..4095
  float rs = 0.f, cs = 0.f;
#pragma unroll
  for (int b = 0; b < 32; ++b) {
    rs += row_part[(size_t)b * N_ + i];
    cs += col_part[(size_t)b * N_ + i];
  }
  int c = hist[labels[i]];
  double term = (double)c * ((double)logf(rs) + (double)logf(cs));
  double sterm = (i < 1024) ? (double)S_part[i] : 0.0;
#pragma unroll
  for (int m = 32; m; m >>= 1) {
    term += __shfl_xor(term, m);
    sterm += __shfl_xor(sterm, m);
  }
  __shared__ double tbuf[4], sb[4];
  int lane = tid & 63, w = tid >> 6;
  if (lane == 0) { tbuf[w] = term; sb[w] = sterm; }
  __syncthreads();
  if (tid == 0) {
    atomicAdd(&accs[0], tbuf[0] + tbuf[1] + tbuf[2] + tbuf[3]);
    atomicAdd(&accs[1], sb[0] + sb[1] + sb[2] + sb[3]);
    __threadfence();
    unsigned old = atomicAdd(cnt, 1u);
    if (old == 15u) {
      double t = atomicAdd(&accs[0], 0.0);
      double s2 = atomicAdd(&accs[1], 0.0);
      out[0] = (float)((t - 2.0 * s2) / (2.0 * (double)N_));
    }
  }
}

extern "C" void kernel_launch(void* const* d_in, const int* in_sizes, int n_in,
                              void* d_out, int out_size, void* d_ws, size_t ws_size,
                              hipStream_t stream) {
  const float* img = (const float*)d_in[0];
  const float* txt = (const float*)d_in[1];
  const int* labels = (const int*)d_in[2];
  float* out = (float*)d_out;
  char* ws = (char*)d_ws;

  // workspace layout (bytes)
  __hip_bfloat16* img_nb = (__hip_bfloat16*)(ws);             //  6,291,456
  __hip_bfloat16* txt_nb = (__hip_bfloat16*)(ws + 6291456);   //  6,291,456
  float* row_part = (float*)(ws + 12582912);                  //    524,288 (32 x 4096)
  float* col_part = (float*)(ws + 13107200);                  //    524,288
  float* S_part = (float*)(ws + 13631488);                    //      4,096
  double* accs = (double*)(ws + 13635584);                    //  16 (+cnt 4)
  unsigned* cnt = (unsigned*)(ws + 13635600);

  hipMemsetAsync(ws + 13635584, 0, 32, stream);  // accs + cnt
  normalize_kernel<<<2 * N_ / 4, 256, 0, stream>>>(img, txt, img_nb, txt_nb);
  gemm_epi_kernel<<<dim3(32, 32), 256, 0, stream>>>(
      (const unsigned short*)img_nb, (const unsigned short*)txt_nb, labels,
      row_part, col_part, S_part);
  reduce_kernel<<<16, 256, 0, stream>>>(row_part, col_part, S_part, labels, accs, cnt, out);
}

// Round 13
// 56.604 us; speedup vs baseline: 1.0480x; 1.0480x over previous
//
#include <hip/hip_runtime.h>
#include <hip/hip_bf16.h>

#define N_ 4096
#define D_ 768
#define NCLS 128
#define BM 128
#define BN 128
#define BK 64
#define NSTEP 12  // D_/BK

typedef __bf16 bf16x8 __attribute__((ext_vector_type(8)));
typedef float f32x16 __attribute__((ext_vector_type(16)));
typedef short s16x8 __attribute__((ext_vector_type(8)));

// Normalize both embedding matrices (blocks [0,N) -> img, [N,2N) -> txt).
__global__ __launch_bounds__(192) void normalize_kernel(
    const float* __restrict__ img, const float* __restrict__ txt,
    __hip_bfloat16* __restrict__ img_nb, __hip_bfloat16* __restrict__ txt_nb) {
  int b = blockIdx.x;
  const float* s;
  __hip_bfloat16* d;
  if (b < N_) {
    s = img + (size_t)b * D_;
    d = img_nb + (size_t)b * D_;
  } else {
    s = txt + (size_t)(b - N_) * D_;
    d = txt_nb + (size_t)(b - N_) * D_;
  }
  int tid = threadIdx.x;
  float4 v = ((const float4*)s)[tid];
  float ss = v.x * v.x + v.y * v.y + v.z * v.z + v.w * v.w;
#pragma unroll
  for (int m = 32; m; m >>= 1) ss += __shfl_xor(ss, m);
  __shared__ float wsum[3];
  int lane = tid & 63, w = tid >> 6;
  if (lane == 0) wsum[w] = ss;
  __syncthreads();
  float inv = 1.0f / fmaxf(sqrtf(wsum[0] + wsum[1] + wsum[2]), 1e-8f);
  ushort4 o;
  o.x = __bfloat16_as_ushort(__float2bfloat16(v.x * inv));
  o.y = __bfloat16_as_ushort(__float2bfloat16(v.y * inv));
  o.z = __bfloat16_as_ushort(__float2bfloat16(v.z * inv));
  o.w = __bfloat16_as_ushort(__float2bfloat16(v.w * inv));
  ((ushort4*)d)[tid] = o;
}

// 128x128-tile bf16 GEMM, double-buffered one-barrier schedule (r11), now with
// mfma_f32_32x32x16_bf16: one b128 fragment read covers 32 rows x 16 k, so a
// 64x64 wave tile needs 8 reads + 8 MFMA per K64-step (vs 16+32 with 16x16x32)
// -- halves LDS fragment traffic (the measured bottleneck: VALUBusy>MfmaUtil).
// Same measured-0-conflict swizzle slot=(2kh+h)^(row&7), rows 128B apart.
// C/D layout (m74/m101-verified): col=lane&31, row=(r&3)+8*(r>>2)+4*(lane>>5).
__global__ __launch_bounds__(256) void gemm_epi_kernel(
    const unsigned short* __restrict__ A, const unsigned short* __restrict__ B,
    const int* __restrict__ labels, float* __restrict__ row_part,
    float* __restrict__ col_part, float* __restrict__ S_part) {
  __shared__ __align__(16) unsigned short As[2][8192];  // [buf][row*8+slot][8]
  __shared__ __align__(16) unsigned short Bs[2][8192];
  __shared__ int labR[BM], labC[BN];
  __shared__ float rbuf[2][BM], cbuf[2][BN];
  __shared__ float sbuf[4];

  const int bx = blockIdx.x, by = blockIdx.y;
  const int tid = threadIdx.x;
  const int lane = tid & 63, wave = tid >> 6;
  const int wr = wave >> 1, wc = wave & 1;
  const int ln = lane & 31, h = lane >> 5;
  const int rowBase = by * BM, colBase = bx * BN;

  if (tid < BM) labR[tid] = labels[rowBase + tid];
  else labC[tid - BM] = labels[colBase + tid - BM];

  // staging: thread t covers chunk col gq=t&7, rows rbase+32j (j=0..3)
  const int gq = tid & 7, rbase = tid >> 3;
  const unsigned short* pa = A + (size_t)(rowBase + rbase) * D_ + gq * 8;
  const unsigned short* pb = B + (size_t)(colBase + rbase) * D_ + gq * 8;
  const int wpos = (rbase * 8 + (gq ^ (rbase & 7))) * 8;  // + j*2048

  f32x16 acc[2][2] = {};  // wave tile 64x64 as 2x2 of 32x32

  // fragment read offsets (ushort index), fixed per thread:
  // A row = wr*64 + mb*32 + ln, slot = (2*kh + h) ^ (ln&7)
  const int lx = ln & 7;
  int aoff[2], boff[2];  // [mb]/[nb], before slot
#pragma unroll
  for (int mb = 0; mb < 2; ++mb) aoff[mb] = (wr * 64 + mb * 32 + ln) * 64;
#pragma unroll
  for (int nb = 0; nb < 2; ++nb) boff[nb] = (wc * 64 + nb * 32 + ln) * 64;

  // prologue: write step 0 into buf0; load step 1 into regs
  s16x8 ra[4], rb[4];
#pragma unroll
  for (int j = 0; j < 4; ++j) {
    ra[j] = *(const s16x8*)(pa + (size_t)(32 * j) * D_);
    rb[j] = *(const s16x8*)(pb + (size_t)(32 * j) * D_);
  }
#pragma unroll
  for (int j = 0; j < 4; ++j) {
    *(s16x8*)&As[0][wpos + j * 2048] = ra[j];
    *(s16x8*)&Bs[0][wpos + j * 2048] = rb[j];
  }
#pragma unroll
  for (int j = 0; j < 4; ++j) {
    ra[j] = *(const s16x8*)(pa + (size_t)(32 * j) * D_ + BK);
    rb[j] = *(const s16x8*)(pb + (size_t)(32 * j) * D_ + BK);
  }
  __syncthreads();  // buf0 resident

  for (int u = 0; u < NSTEP; ++u) {
    const unsigned short* as_ = As[u & 1];
    const unsigned short* bs_ = Bs[u & 1];
    bf16x8 a0[2], b0[2];
    {  // kh=0 fragment reads FIRST (slot = h ^ lx)
      const int sl = (h ^ lx) * 8;
#pragma unroll
      for (int mb = 0; mb < 2; ++mb) a0[mb] = *(const bf16x8*)&as_[aoff[mb] + sl];
#pragma unroll
      for (int nb = 0; nb < 2; ++nb) b0[nb] = *(const bf16x8*)&bs_[boff[nb] + sl];
    }
    if (u + 1 < NSTEP) {  // ds_write u+1 into other buffer; drains under MFMA
      unsigned short* aw = As[(u + 1) & 1];
      unsigned short* bw = Bs[(u + 1) & 1];
#pragma unroll
      for (int j = 0; j < 4; ++j) {
        *(s16x8*)&aw[wpos + j * 2048] = ra[j];
        *(s16x8*)&bw[wpos + j * 2048] = rb[j];
      }
    }
#pragma unroll
    for (int mb = 0; mb < 2; ++mb)
#pragma unroll
      for (int nb = 0; nb < 2; ++nb)
        acc[mb][nb] = __builtin_amdgcn_mfma_f32_32x32x16_bf16(a0[mb], b0[nb], acc[mb][nb], 0, 0, 0);
    {  // kh=1 (slot = (2+h) ^ lx)
      const int sl = ((2 + h) ^ lx) * 8;
#pragma unroll
      for (int mb = 0; mb < 2; ++mb) a0[mb] = *(const bf16x8*)&as_[aoff[mb] + sl];
#pragma unroll
      for (int nb = 0; nb < 2; ++nb) b0[nb] = *(const bf16x8*)&bs_[boff[nb] + sl];
    }
#pragma unroll
    for (int mb = 0; mb < 2; ++mb)
#pragma unroll
      for (int nb = 0; nb < 2; ++nb)
        acc[mb][nb] = __builtin_amdgcn_mfma_f32_32x32x16_bf16(a0[mb], b0[nb], acc[mb][nb], 0, 0, 0);
    if (u + 2 < NSTEP) {  // global prefetch (staging regs freed by writes above)
      const int k0 = (u + 2) * BK;
#pragma unroll
      for (int j = 0; j < 4; ++j) {
        ra[j] = *(const s16x8*)(pa + (size_t)(32 * j) * D_ + k0);
        rb[j] = *(const s16x8*)(pb + (size_t)(32 * j) * D_ + k0);
      }
    }
    __syncthreads();
  }

  // epilogue: C layout col = C0+ln, row = R0 + (r&3)+8*(r>>2)+4*h
  const float scale = 14.285714285714286f;  // 1/0.07
  const int lc0 = labC[wc * 64 + ln], lc1 = labC[wc * 64 + 32 + ln];
  float sPart = 0.f;
  float colAcc[2] = {0.f, 0.f};
#pragma unroll
  for (int mb = 0; mb < 2; ++mb) {
#pragma unroll
    for (int r = 0; r < 16; ++r) {
      const int row = wr * 64 + mb * 32 + (r & 3) + ((r >> 2) * 8) + h * 4;
      const int lr = labR[row];
      float v0 = acc[mb][0][r] * scale;
      float v1 = acc[mb][1][r] * scale;
      float e0 = __expf(v0), e1 = __expf(v1);
      colAcc[0] += e0;
      colAcc[1] += e1;
      if (lr == lc0) sPart += v0;
      if (lr == lc1) sPart += v1;
      float rv = e0 + e1;
      rv += __shfl_xor(rv, 1);
      rv += __shfl_xor(rv, 2);
      rv += __shfl_xor(rv, 4);
      rv += __shfl_xor(rv, 8);
      rv += __shfl_xor(rv, 16);
      if (ln == 0) rbuf[wc][row] = rv;
    }
  }
#pragma unroll
  for (int nb = 0; nb < 2; ++nb) {
    float x = colAcc[nb] + __shfl_xor(colAcc[nb], 32);
    if (h == 0) cbuf[wr][wc * 64 + nb * 32 + ln] = x;
  }
  float s = sPart;
#pragma unroll
  for (int m = 32; m; m >>= 1) s += __shfl_xor(s, m);
  if (lane == 0) sbuf[wave] = s;
  __syncthreads();
  if (tid < BM)
    row_part[(size_t)bx * N_ + rowBase + tid] = rbuf[0][tid] + rbuf[1][tid];
  else
    col_part[(size_t)by * N_ + colBase + (tid - BM)] = cbuf[0][tid - BM] + cbuf[1][tid - BM];
  if (tid == 0) S_part[by * 32 + bx] = sbuf[0] + sbuf[1] + sbuf[2] + sbuf[3];
}

// Per-block local histogram; partials out (no atomics, no memset needed)
__global__ __launch_bounds__(256) void reduce_kernel(
    const float* __restrict__ row_part, const float* __restrict__ col_part,
    const float* __restrict__ S_part, const int* __restrict__ labels,
    double* __restrict__ partials) {
  __shared__ int hist[NCLS];
  int tid = threadIdx.x;
  if (tid < NCLS) hist[tid] = 0;
  __syncthreads();
  for (int j = tid; j < N_; j += 256) atomicAdd(&hist[labels[j]], 1);
  __syncthreads();

  int i = blockIdx.x * 256 + tid;  // 0..4095
  float rs = 0.f, cs = 0.f;
#pragma unroll
  for (int b = 0; b < 32; ++b) {
    rs += row_part[(size_t)b * N_ + i];
    cs += col_part[(size_t)b * N_ + i];
  }
  int cnt = hist[labels[i]];
  double term = (double)cnt * ((double)logf(rs) + (double)logf(cs));
  double sterm = (i < 1024) ? (double)S_part[i] : 0.0;
#pragma unroll
  for (int m = 32; m; m >>= 1) {
    term += __shfl_xor(term, m);
    sterm += __shfl_xor(sterm, m);
  }
  __shared__ double tbuf[4], sb[4];
  int lane = tid & 63, w = tid >> 6;
  if (lane == 0) { tbuf[w] = term; sb[w] = sterm; }
  __syncthreads();
  if (tid == 0) {
    partials[blockIdx.x] = tbuf[0] + tbuf[1] + tbuf[2] + tbuf[3];
    partials[16 + blockIdx.x] = sb[0] + sb[1] + sb[2] + sb[3];
  }
}

__global__ void final_kernel(const double* __restrict__ partials, float* __restrict__ out) {
  double t = 0.0, s = 0.0;
#pragma unroll
  for (int i = 0; i < 16; ++i) {
    t += partials[i];
    s += partials[16 + i];
  }
  out[0] = (float)((t - 2.0 * s) / (2.0 * (double)N_));
}

extern "C" void kernel_launch(void* const* d_in, const int* in_sizes, int n_in,
                              void* d_out, int out_size, void* d_ws, size_t ws_size,
                              hipStream_t stream) {
  const float* img = (const float*)d_in[0];
  const float* txt = (const float*)d_in[1];
  const int* labels = (const int*)d_in[2];
  float* out = (float*)d_out;
  char* ws = (char*)d_ws;

  // workspace layout (bytes)
  __hip_bfloat16* img_nb = (__hip_bfloat16*)(ws);             //  6,291,456
  __hip_bfloat16* txt_nb = (__hip_bfloat16*)(ws + 6291456);   //  6,291,456
  float* row_part = (float*)(ws + 12582912);                  //    524,288 (32 x 4096)
  float* col_part = (float*)(ws + 13107200);                  //    524,288
  float* S_part = (float*)(ws + 13631488);                    //      4,096
  double* partials = (double*)(ws + 13635584);                //        256

  normalize_kernel<<<2 * N_, 192, 0, stream>>>(img, txt, img_nb, txt_nb);
  gemm_epi_kernel<<<dim3(32, 32), 256, 0, stream>>>(
      (const unsigned short*)img_nb, (const unsigned short*)txt_nb, labels,
      row_part, col_part, S_part);
  reduce_kernel<<<16, 256, 0, stream>>>(row_part, col_part, S_part, labels, partials);
  final_kernel<<<1, 1, 0, stream>>>(partials, out);
}

// Round 14
// 53.941 us; speedup vs baseline: 1.0998x; 1.0494x over previous
//
#include <hip/hip_runtime.h>
#include <hip/hip_bf16.h>

#define N_ 4096
#define D_ 768
#define NCLS 128
#define BM 128
#define BN 128
#define BK 64
#define NSTEP 12  // D_/BK

typedef __bf16 bf16x8 __attribute__((ext_vector_type(8)));
typedef float f32x4 __attribute__((ext_vector_type(4)));
typedef short s16x8 __attribute__((ext_vector_type(8)));

// Normalize both embedding matrices (blocks [0,N) -> img, [N,2N) -> txt).
// Block 0 also zeroes the reduce accumulators (no memset dispatch needed;
// normalize completes before reduce in stream order).
__global__ __launch_bounds__(192) void normalize_kernel(
    const float* __restrict__ img, const float* __restrict__ txt,
    __hip_bfloat16* __restrict__ img_nb, __hip_bfloat16* __restrict__ txt_nb,
    double* __restrict__ accs, unsigned* __restrict__ cnt) {
  int b = blockIdx.x;
  if (b == 0 && threadIdx.x == 0) {
    accs[0] = 0.0;
    accs[1] = 0.0;
    *cnt = 0u;
  }
  const float* s;
  __hip_bfloat16* d;
  if (b < N_) {
    s = img + (size_t)b * D_;
    d = img_nb + (size_t)b * D_;
  } else {
    s = txt + (size_t)(b - N_) * D_;
    d = txt_nb + (size_t)(b - N_) * D_;
  }
  int tid = threadIdx.x;
  float4 v = ((const float4*)s)[tid];
  float ss = v.x * v.x + v.y * v.y + v.z * v.z + v.w * v.w;
#pragma unroll
  for (int m = 32; m; m >>= 1) ss += __shfl_xor(ss, m);
  __shared__ float wsum[3];
  int lane = tid & 63, w = tid >> 6;
  if (lane == 0) wsum[w] = ss;
  __syncthreads();
  float inv = 1.0f / fmaxf(sqrtf(wsum[0] + wsum[1] + wsum[2]), 1e-8f);
  ushort4 o;
  o.x = __bfloat16_as_ushort(__float2bfloat16(v.x * inv));
  o.y = __bfloat16_as_ushort(__float2bfloat16(v.y * inv));
  o.z = __bfloat16_as_ushort(__float2bfloat16(v.z * inv));
  o.w = __bfloat16_as_ushort(__float2bfloat16(v.w * inv));
  ((ushort4*)d)[tid] = o;
}

// 128x128-tile bf16 GEMM (r11: double-buffered, one barrier/step, read-first
// order, measured-0-conflict swizzle pos(row,g)=row*8+(g^(row&7))), plus an
// XCD column-stripe block swizzle: linear id -> xcd=lin&7 owns bx in
// [xcd*4, xcd*4+4) for all by, so each XCD's 4 B-panels (~800KB) stay L2-hot.
__global__ __launch_bounds__(256) void gemm_epi_kernel(
    const unsigned short* __restrict__ A, const unsigned short* __restrict__ B,
    const int* __restrict__ labels, float* __restrict__ row_part,
    float* __restrict__ col_part, float* __restrict__ S_part) {
  __shared__ __align__(16) unsigned short As[2][8192];
  __shared__ __align__(16) unsigned short Bs[2][8192];
  __shared__ int labR[BM], labC[BN];
  __shared__ float rbuf[2][BM], cbuf[2][BN];
  __shared__ float sbuf[4];

  // XCD-aware remap (bijective on 0..1023; grid 1024 % 8 == 0)
  const int lin = blockIdx.y * 32 + blockIdx.x;
  const int xcd = lin & 7, idx = lin >> 3;
  const int bx = xcd * 4 + (idx & 3), by = idx >> 2;

  const int tid = threadIdx.x;
  const int lane = tid & 63, wave = tid >> 6;
  const int wr = wave >> 1, wc = wave & 1;
  const int g = lane >> 4, fr = lane & 15;
  const int rowBase = by * BM, colBase = bx * BN;

  if (tid < BM) labR[tid] = labels[rowBase + tid];
  else labC[tid - BM] = labels[colBase + tid - BM];

  const int gq = tid & 7, rbase = tid >> 3;
  const unsigned short* pa = A + (size_t)(rowBase + rbase) * D_ + gq * 8;
  const unsigned short* pb = B + (size_t)(colBase + rbase) * D_ + gq * 8;
  const int wpos = (rbase * 8 + (gq ^ (rbase & 7))) * 8;  // + j*2048

  f32x4 acc[4][4] = {};

  // prologue: write step 0 into buf0; load step 1 into regs
  s16x8 ra[4], rb[4];
#pragma unroll
  for (int j = 0; j < 4; ++j) {
    ra[j] = *(const s16x8*)(pa + (size_t)(32 * j) * D_);
    rb[j] = *(const s16x8*)(pb + (size_t)(32 * j) * D_);
  }
#pragma unroll
  for (int j = 0; j < 4; ++j) {
    *(s16x8*)&As[0][wpos + j * 2048] = ra[j];
    *(s16x8*)&Bs[0][wpos + j * 2048] = rb[j];
  }
#pragma unroll
  for (int j = 0; j < 4; ++j) {
    ra[j] = *(const s16x8*)(pa + (size_t)(32 * j) * D_ + BK);
    rb[j] = *(const s16x8*)(pb + (size_t)(32 * j) * D_ + BK);
  }
  __syncthreads();  // buf0 resident

  for (int u = 0; u < NSTEP; ++u) {
    const unsigned short* as_ = As[u & 1];
    const unsigned short* bs_ = Bs[u & 1];
    bf16x8 af[4], bf[4];
    {  // ks=0 fragment reads FIRST
      const int sw = g ^ (fr & 7);
#pragma unroll
      for (int m = 0; m < 4; ++m)
        af[m] = *(const bf16x8*)&as_[((wr * 64 + m * 16 + fr) * 8 + sw) * 8];
#pragma unroll
      for (int n = 0; n < 4; ++n)
        bf[n] = *(const bf16x8*)&bs_[((wc * 64 + n * 16 + fr) * 8 + sw) * 8];
    }
    if (u + 1 < NSTEP) {  // write u+1 into other buffer (drains under MFMA ks0)
      unsigned short* aw = As[(u + 1) & 1];
      unsigned short* bw = Bs[(u + 1) & 1];
#pragma unroll
      for (int j = 0; j < 4; ++j) {
        *(s16x8*)&aw[wpos + j * 2048] = ra[j];
        *(s16x8*)&bw[wpos + j * 2048] = rb[j];
      }
    }
#pragma unroll
    for (int m = 0; m < 4; ++m)
#pragma unroll
      for (int n = 0; n < 4; ++n)
        acc[m][n] = __builtin_amdgcn_mfma_f32_16x16x32_bf16(af[m], bf[n], acc[m][n], 0, 0, 0);
    {  // ks=1
      const int sw = (4 + g) ^ (fr & 7);
#pragma unroll
      for (int m = 0; m < 4; ++m)
        af[m] = *(const bf16x8*)&as_[((wr * 64 + m * 16 + fr) * 8 + sw) * 8];
#pragma unroll
      for (int n = 0; n < 4; ++n)
        bf[n] = *(const bf16x8*)&bs_[((wc * 64 + n * 16 + fr) * 8 + sw) * 8];
    }
#pragma unroll
    for (int m = 0; m < 4; ++m)
#pragma unroll
      for (int n = 0; n < 4; ++n)
        acc[m][n] = __builtin_amdgcn_mfma_f32_16x16x32_bf16(af[m], bf[n], acc[m][n], 0, 0, 0);
    if (u + 2 < NSTEP) {  // global prefetch (regs freed by the writes above)
      const int k0 = (u + 2) * BK;
#pragma unroll
      for (int j = 0; j < 4; ++j) {
        ra[j] = *(const s16x8*)(pa + (size_t)(32 * j) * D_ + k0);
        rb[j] = *(const s16x8*)(pb + (size_t)(32 * j) * D_ + k0);
      }
    }
    __syncthreads();
  }

  const float scale = 14.285714285714286f;  // 1/0.07
  float sPart = 0.f;
  float colAcc[4] = {0.f, 0.f, 0.f, 0.f};
#pragma unroll
  for (int m = 0; m < 4; ++m) {
    float ra2[4] = {0.f, 0.f, 0.f, 0.f};
#pragma unroll
    for (int n = 0; n < 4; ++n) {
      int col = wc * 64 + n * 16 + fr;
      int lc = labC[col];
#pragma unroll
      for (int r = 0; r < 4; ++r) {
        float v = acc[m][n][r] * scale;
        float e = __expf(v);
        ra2[r] += e;
        colAcc[n] += e;
        int row = wr * 64 + m * 16 + g * 4 + r;
        if (labR[row] == lc) sPart += v;
      }
    }
#pragma unroll
    for (int r = 0; r < 4; ++r) {
      float x = ra2[r];
      x += __shfl_xor(x, 1);
      x += __shfl_xor(x, 2);
      x += __shfl_xor(x, 4);
      x += __shfl_xor(x, 8);
      if (fr == 0) rbuf[wc][wr * 64 + m * 16 + g * 4 + r] = x;
    }
  }
#pragma unroll
  for (int n = 0; n < 4; ++n) {
    float x = colAcc[n];
    x += __shfl_xor(x, 16);
    x += __shfl_xor(x, 32);
    if (g == 0) cbuf[wr][wc * 64 + n * 16 + fr] = x;
  }
  float s = sPart;
#pragma unroll
  for (int m = 32; m; m >>= 1) s += __shfl_xor(s, m);
  if (lane == 0) sbuf[wave] = s;
  __syncthreads();
  if (tid < BM)
    row_part[(size_t)bx * N_ + rowBase + tid] = rbuf[0][tid] + rbuf[1][tid];
  else
    col_part[(size_t)by * N_ + colBase + (tid - BM)] = cbuf[0][tid - BM] + cbuf[1][tid - BM];
  if (tid == 0) S_part[by * 32 + bx] = sbuf[0] + sbuf[1] + sbuf[2] + sbuf[3];
}

// Final reduction merged: per-block hist + partial sums -> device-scope double
// atomics; last-done block writes the scalar loss (accs/cnt zeroed by normalize).
__global__ __launch_bounds__(256) void reduce_kernel(
    const float* __restrict__ row_part, const float* __restrict__ col_part,
    const float* __restrict__ S_part, const int* __restrict__ labels,
    double* __restrict__ accs, unsigned* __restrict__ cnt, float* __restrict__ out) {
  __shared__ int hist[NCLS];
  int tid = threadIdx.x;
  if (tid < NCLS) hist[tid] = 0;
  __syncthreads();
  for (int j = tid; j < N_; j += 256) atomicAdd(&hist[labels[j]], 1);
  __syncthreads();

  int i = blockIdx.x * 256 + tid;  // 0..4095
  float rs = 0.f, cs = 0.f;
#pragma unroll
  for (int b = 0; b < 32; ++b) {
    rs += row_part[(size_t)b * N_ + i];
    cs += col_part[(size_t)b * N_ + i];
  }
  int c = hist[labels[i]];
  double term = (double)c * ((double)logf(rs) + (double)logf(cs));
  double sterm = (i < 1024) ? (double)S_part[i] : 0.0;
#pragma unroll
  for (int m = 32; m; m >>= 1) {
    term += __shfl_xor(term, m);
    sterm += __shfl_xor(sterm, m);
  }
  __shared__ double tbuf[4], sb[4];
  int lane = tid & 63, w = tid >> 6;
  if (lane == 0) { tbuf[w] = term; sb[w] = sterm; }
  __syncthreads();
  if (tid == 0) {
    atomicAdd(&accs[0], tbuf[0] + tbuf[1] + tbuf[2] + tbuf[3]);
    atomicAdd(&accs[1], sb[0] + sb[1] + sb[2] + sb[3]);
    __threadfence();
    unsigned old = atomicAdd(cnt, 1u);
    if (old == 15u) {
      double t = atomicAdd(&accs[0], 0.0);   // device-scope read
      double s2 = atomicAdd(&accs[1], 0.0);
      out[0] = (float)((t - 2.0 * s2) / (2.0 * (double)N_));
    }
  }
}

extern "C" void kernel_launch(void* const* d_in, const int* in_sizes, int n_in,
                              void* d_out, int out_size, void* d_ws, size_t ws_size,
                              hipStream_t stream) {
  const float* img = (const float*)d_in[0];
  const float* txt = (const float*)d_in[1];
  const int* labels = (const int*)d_in[2];
  float* out = (float*)d_out;
  char* ws = (char*)d_ws;

  // workspace layout (bytes)
  __hip_bfloat16* img_nb = (__hip_bfloat16*)(ws);             //  6,291,456
  __hip_bfloat16* txt_nb = (__hip_bfloat16*)(ws + 6291456);   //  6,291,456
  float* row_part = (float*)(ws + 12582912);                  //    524,288 (32 x 4096)
  float* col_part = (float*)(ws + 13107200);                  //    524,288
  float* S_part = (float*)(ws + 13631488);                    //      4,096
  double* accs = (double*)(ws + 13635584);                    //  16 (+cnt 4)
  unsigned* cnt = (unsigned*)(ws + 13635600);

  normalize_kernel<<<2 * N_, 192, 0, stream>>>(img, txt, img_nb, txt_nb, accs, cnt);
  gemm_epi_kernel<<<dim3(32, 32), 256, 0, stream>>>(
      (const unsigned short*)img_nb, (const unsigned short*)txt_nb, labels,
      row_part, col_part, S_part);
  reduce_kernel<<<16, 256, 0, stream>>>(row_part, col_part, S_part, labels, accs, cnt, out);
}